// Round 1
// baseline (531.096 us; speedup 1.0000x reference)
//
#include <hip/hip_runtime.h>
#include <hip/hip_bf16.h>
#include <math.h>

#define B_ROWS 16384
#define IN_SIZE 512
#define LATENT 256
#define PC 16
#define EPS_SIM 1e-4f
#define LOG_MIN_F (-18.420680743952367f)

#define KL_IDX  (B_ROWS + B_ROWS * IN_SIZE)      // 8404992
#define OR_IDX  (KL_IDX + 1)

#define BM 128
#define BN 128
#define BK 16
#define LPAD 132   // padded LDS row stride (floats): keeps 16B alignment, spreads banks

// ---------------------------------------------------------------------------
// init: zero S[] and the two scalar-loss accumulator slots in d_out
// ---------------------------------------------------------------------------
__global__ void init_kernel(float* __restrict__ S, float* __restrict__ out)
{
    int i = blockIdx.x * 256 + threadIdx.x;
    if (i < B_ROWS) S[i] = 0.0f;
    if (i == 0) { out[KL_IDX] = 0.0f; out[OR_IDX] = 0.0f; }
}

// ---------------------------------------------------------------------------
// C[M x ldc] = act(A[M x K] @ W[N x K]^T + bias)
// MODE 0: relu store   MODE 1: mu store (n<256) + S accumulation (n>=256)
// MODE 3: tanh store
// ---------------------------------------------------------------------------
template<int MODE>
__global__ __launch_bounds__(256)
void gemm_nt(const float* __restrict__ A, const float* __restrict__ W,
             const float* __restrict__ bias, float* __restrict__ C,
             float* __restrict__ S, int K, int ldc)
{
    __shared__ __align__(16) float As[BK][LPAD];
    __shared__ __align__(16) float Ws[BK][LPAD];

    const int t  = threadIdx.x;
    const int bm = blockIdx.x * BM;
    const int bn = blockIdx.y * BN;

    // global->LDS staging map: each thread owns one row, 8 consecutive k
    const int lrow = t >> 1;
    const int lkq  = (t & 1) * 8;
    const float* Ap = A + (size_t)(bm + lrow) * K + lkq;
    const float* Wp = W + (size_t)(bn + lrow) * K + lkq;

    // compute micro-tile map: 8x8 outputs split as {tm..tm+3, 64+tm..64+tm+3}
    const int tm = (t & 15) * 4;
    const int tn = (t >> 4) * 4;

    float acc[8][8];
#pragma unroll
    for (int i = 0; i < 8; ++i)
#pragma unroll
        for (int j = 0; j < 8; ++j) acc[i][j] = 0.0f;

    const int T = K / BK;
    float ra[8], rw[8], ra2[8], rw2[8];
    *(float4*)&ra[0] = *(const float4*)(Ap);
    *(float4*)&ra[4] = *(const float4*)(Ap + 4);
    *(float4*)&rw[0] = *(const float4*)(Wp);
    *(float4*)&rw[4] = *(const float4*)(Wp + 4);

    for (int tt = 0; tt < T; ++tt) {
        __syncthreads();
#pragma unroll
        for (int j = 0; j < 8; ++j) {
            As[lkq + j][lrow] = ra[j];
            Ws[lkq + j][lrow] = rw[j];
        }
        __syncthreads();

        if (tt + 1 < T) {
            Ap += BK; Wp += BK;
            *(float4*)&ra2[0] = *(const float4*)(Ap);
            *(float4*)&ra2[4] = *(const float4*)(Ap + 4);
            *(float4*)&rw2[0] = *(const float4*)(Wp);
            *(float4*)&rw2[4] = *(const float4*)(Wp + 4);
        }

#pragma unroll
        for (int k = 0; k < BK; ++k) {
            float a[8], b[8];
            *(float4*)&a[0] = *(const float4*)&As[k][tm];
            *(float4*)&a[4] = *(const float4*)&As[k][tm + 64];
            *(float4*)&b[0] = *(const float4*)&Ws[k][tn];
            *(float4*)&b[4] = *(const float4*)&Ws[k][tn + 64];
#pragma unroll
            for (int i = 0; i < 8; ++i)
#pragma unroll
                for (int j = 0; j < 8; ++j)
                    acc[i][j] = fmaf(a[i], b[j], acc[i][j]);
        }

#pragma unroll
        for (int j = 0; j < 8; ++j) { ra[j] = ra2[j]; rw[j] = rw2[j]; }
    }

    // epilogue
    float bv[8];
#pragma unroll
    for (int j = 0; j < 8; ++j) {
        int n = bn + ((j < 4) ? (tn + j) : (64 + tn + j - 4));
        bv[j] = bias[n];
    }

#pragma unroll
    for (int i = 0; i < 8; ++i) {
        int m = bm + ((i < 4) ? (tm + i) : (64 + tm + i - 4));
        float v[8];
#pragma unroll
        for (int j = 0; j < 8; ++j) v[j] = acc[i][j] + bv[j];

        if (MODE == 0) {
#pragma unroll
            for (int j = 0; j < 8; ++j) v[j] = fmaxf(v[j], 0.0f);
            float* Crow = C + (size_t)m * ldc;
            *(float4*)(Crow + bn + tn)      = *(float4*)&v[0];
            *(float4*)(Crow + bn + 64 + tn) = *(float4*)&v[4];
        } else if (MODE == 3) {
#pragma unroll
            for (int j = 0; j < 8; ++j) v[j] = tanhf(v[j]);
            float* Crow = C + (size_t)m * ldc;
            *(float4*)(Crow + bn + tn)      = *(float4*)&v[0];
            *(float4*)(Crow + bn + 64 + tn) = *(float4*)&v[4];
        } else { // MODE 1
            if (bn < 256) {
                float* Crow = C + (size_t)m * ldc;   // mu, ldc = 256
                *(float4*)(Crow + bn + tn)      = *(float4*)&v[0];
                *(float4*)(Crow + bn + 64 + tn) = *(float4*)&v[4];
            } else {
                float rs = 0.0f;
#pragma unroll
                for (int j = 0; j < 8; ++j) {
                    float lv = fminf(fmaxf(v[j], LOG_MIN_F), -LOG_MIN_F);
                    rs += 0.5f * __expf(lv) - 0.5f * lv - 0.5f;
                }
                atomicAdd(&S[m], rs * (1.0f / (float)LATENT));
            }
        }
    }
}

// ---------------------------------------------------------------------------
// per-row prototype math: one wave per row
// out[b] = sum_p sim * W_last[idx];  kl_loss += (sum klw / sum sim*mask)/B
// ---------------------------------------------------------------------------
__global__ __launch_bounds__(256)
void proto_kernel(const float* __restrict__ mu, const float* __restrict__ S,
                  const int* __restrict__ tcls, const float* __restrict__ protos,
                  const float* __restrict__ Wlast, float* __restrict__ out,
                  float* __restrict__ kl_out)
{
    int wave = (blockIdx.x * blockDim.x + threadIdx.x) >> 6;
    int lane = threadIdx.x & 63;
    if (wave >= B_ROWS) return;
    int b = wave;

    const float* murow = mu + (size_t)b * LATENT;
    float m0 = murow[lane];
    float m1 = murow[lane + 64];
    float m2 = murow[lane + 128];
    float m3 = murow[lane + 192];

    int cls = tcls[b];
    const float* pbase = protos + (size_t)cls * PC * LATENT;
    float Sb = S[b];

    float outv = 0.0f, num = 0.0f, den = 0.0f;
#pragma unroll
    for (int p = 0; p < PC; ++p) {
        const float* pr = pbase + p * LATENT;
        float d0 = m0 - pr[lane];
        float d1 = m1 - pr[lane + 64];
        float d2 = m2 - pr[lane + 128];
        float d3 = m3 - pr[lane + 192];
        float dd = d0 * d0 + d1 * d1 + d2 * d2 + d3 * d3;
#pragma unroll
        for (int off = 32; off; off >>= 1) dd += __shfl_xor(dd, off, 64);
        float d   = sqrtf(dd);
        float sim = logf((d + 1.0f) / (d + EPS_SIM));
        float kl  = Sb + dd * (0.5f / (float)LATENT);
        float klw = kl * sim;
        num += klw;
        den += (klw > 0.0f) ? sim : 0.0f;
        outv += sim * Wlast[cls * PC + p];
    }
    if (lane == 0) {
        out[b] = outv;
        atomicAdd(kl_out, (num / den) * (1.0f / (float)B_ROWS));
    }
}

// ---------------------------------------------------------------------------
// ortho loss: one block per class
// ---------------------------------------------------------------------------
__global__ __launch_bounds__(256)
void ortho_kernel(const float* __restrict__ protos, float* __restrict__ ortho_out)
{
    int c = blockIdx.x;
    __shared__ float pk[PC][LATENT + 1];
    __shared__ float red[256];
    int t = threadIdx.x;

    for (int i = t; i < PC * LATENT; i += 256)
        pk[i >> 8][i & 255] = protos[c * PC * LATENT + i];
    __syncthreads();

    // center column t across the 16 prototypes (t in [0,256))
    float mean = 0.0f;
    for (int i = 0; i < PC; ++i) mean += pk[i][t];
    mean *= (1.0f / (float)PC);
    for (int i = 0; i < PC; ++i) pk[i][t] -= mean;
    __syncthreads();

    int i = t >> 4, j = t & 15;
    float g = 0.0f;
    for (int l = 0; l < LATENT; ++l) g += pk[i][l] * pk[j][l];
    g -= (i == j) ? 1.0f : 0.0f;

    red[t] = g * g;
    __syncthreads();
    for (int s = 128; s; s >>= 1) {
        if (t < s) red[t] += red[t + s];
        __syncthreads();
    }
    if (t == 0) atomicAdd(ortho_out, sqrtf(red[0]) * (1.0f / 8.0f));
}

// ---------------------------------------------------------------------------
extern "C" void kernel_launch(void* const* d_in, const int* in_sizes, int n_in,
                              void* d_out, int out_size, void* d_ws, size_t ws_size,
                              hipStream_t stream)
{
    const float* x      = (const float*)d_in[0];
    const int*   tcls   = (const int*)  d_in[1];
    const float* protos = (const float*)d_in[2];
    const float* W1     = (const float*)d_in[3];
    const float* b1     = (const float*)d_in[4];
    const float* W2     = (const float*)d_in[5];
    const float* b2     = (const float*)d_in[6];
    const float* Wd1    = (const float*)d_in[7];
    const float* bd1    = (const float*)d_in[8];
    const float* Wd2    = (const float*)d_in[9];
    const float* bd2    = (const float*)d_in[10];
    const float* Wlast  = (const float*)d_in[11];

    float* out     = (float*)d_out;
    float* decoded = out + B_ROWS;

    float* ws = (float*)d_ws;
    float* h  = ws;                                    // B x 512 (reused as dh later)
    float* mu = ws + (size_t)B_ROWS * IN_SIZE;         // B x 256
    float* S  = mu + (size_t)B_ROWS * LATENT;          // B
    float* dh = ws;                                    // B x 256 (overwrites h)

    hipLaunchKernelGGL(init_kernel, dim3(64), dim3(256), 0, stream, S, out);

    // h = relu(x @ W1^T + b1)
    hipLaunchKernelGGL((gemm_nt<0>), dim3(B_ROWS / BM, IN_SIZE / BN), dim3(256), 0, stream,
                       x, W1, b1, h, (float*)nullptr, IN_SIZE, IN_SIZE);
    // conv = h @ W2^T + b2 -> mu (cols<256), S (cols>=256)
    hipLaunchKernelGGL((gemm_nt<1>), dim3(B_ROWS / BM, IN_SIZE / BN), dim3(256), 0, stream,
                       h, W2, b2, mu, S, IN_SIZE, LATENT);
    // prototype distances, sim, out, kl_loss
    hipLaunchKernelGGL(proto_kernel, dim3(B_ROWS / 4), dim3(256), 0, stream,
                       mu, S, tcls, protos, Wlast, out, out + KL_IDX);
    // dh = relu(mu @ Wd1^T + bd1)
    hipLaunchKernelGGL((gemm_nt<0>), dim3(B_ROWS / BM, LATENT / BN), dim3(256), 0, stream,
                       mu, Wd1, bd1, dh, (float*)nullptr, LATENT, LATENT);
    // decoded = tanh(dh @ Wd2^T + bd2)
    hipLaunchKernelGGL((gemm_nt<3>), dim3(B_ROWS / BM, IN_SIZE / BN), dim3(256), 0, stream,
                       dh, Wd2, bd2, decoded, (float*)nullptr, LATENT, IN_SIZE);
    // ortho loss
    hipLaunchKernelGGL(ortho_kernel, dim3(8), dim3(256), 0, stream, protos, out + OR_IDX);
}

// Round 2
// 351.062 us; speedup vs baseline: 1.5128x; 1.5128x over previous
//
#include <hip/hip_runtime.h>
#include <hip/hip_bf16.h>
#include <math.h>

#define B_ROWS 16384
#define IN_SIZE 512
#define LATENT 256
#define PC 16
#define EPS_SIM 1e-4f
#define LOG_MIN_F (-18.420680743952367f)

#define KL_IDX  (B_ROWS + B_ROWS * IN_SIZE)      // 8404992
#define OR_IDX  (KL_IDX + 1)

#define BM 128
#define BN 128
#define BK 16
#define LPAD 132   // padded LDS row stride (floats): keeps 16B alignment, spreads banks

// ---------------------------------------------------------------------------
// init: zero S[] and the two scalar-loss accumulator slots in d_out
// ---------------------------------------------------------------------------
__global__ void init_kernel(float* __restrict__ S, float* __restrict__ out)
{
    int i = blockIdx.x * 256 + threadIdx.x;
    if (i < B_ROWS) S[i] = 0.0f;
    if (i == 0) { out[KL_IDX] = 0.0f; out[OR_IDX] = 0.0f; }
}

// ---------------------------------------------------------------------------
// C[M x ldc] = act(A[M x K] @ W[N x K]^T + bias)
// MODE 0: relu store   MODE 1: mu store (n<256) + S accumulation (n>=256)
// MODE 3: tanh store
// ---------------------------------------------------------------------------
template<int MODE>
__global__ __launch_bounds__(256)
void gemm_nt(const float* __restrict__ A, const float* __restrict__ W,
             const float* __restrict__ bias, float* __restrict__ C,
             float* __restrict__ S, int K, int ldc)
{
    __shared__ __align__(16) float As[BK][LPAD];
    __shared__ __align__(16) float Ws[BK][LPAD];

    const int t  = threadIdx.x;
    const int bm = blockIdx.x * BM;
    const int bn = blockIdx.y * BN;

    // global->LDS staging map: each thread owns one row, 8 consecutive k
    const int lrow = t >> 1;
    const int lkq  = (t & 1) * 8;
    const float* Ap = A + (size_t)(bm + lrow) * K + lkq;
    const float* Wp = W + (size_t)(bn + lrow) * K + lkq;

    // compute micro-tile map: 8x8 outputs split as {tm..tm+3, 64+tm..64+tm+3}
    const int tm = (t & 15) * 4;
    const int tn = (t >> 4) * 4;

    float acc[8][8];
#pragma unroll
    for (int i = 0; i < 8; ++i)
#pragma unroll
        for (int j = 0; j < 8; ++j) acc[i][j] = 0.0f;

    const int T = K / BK;
    float ra[8], rw[8], ra2[8], rw2[8];
    *(float4*)&ra[0] = *(const float4*)(Ap);
    *(float4*)&ra[4] = *(const float4*)(Ap + 4);
    *(float4*)&rw[0] = *(const float4*)(Wp);
    *(float4*)&rw[4] = *(const float4*)(Wp + 4);

    for (int tt = 0; tt < T; ++tt) {
        __syncthreads();
#pragma unroll
        for (int j = 0; j < 8; ++j) {
            As[lkq + j][lrow] = ra[j];
            Ws[lkq + j][lrow] = rw[j];
        }
        __syncthreads();

        if (tt + 1 < T) {
            Ap += BK; Wp += BK;
            *(float4*)&ra2[0] = *(const float4*)(Ap);
            *(float4*)&ra2[4] = *(const float4*)(Ap + 4);
            *(float4*)&rw2[0] = *(const float4*)(Wp);
            *(float4*)&rw2[4] = *(const float4*)(Wp + 4);
        }

#pragma unroll
        for (int k = 0; k < BK; ++k) {
            float a[8], b[8];
            *(float4*)&a[0] = *(const float4*)&As[k][tm];
            *(float4*)&a[4] = *(const float4*)&As[k][tm + 64];
            *(float4*)&b[0] = *(const float4*)&Ws[k][tn];
            *(float4*)&b[4] = *(const float4*)&Ws[k][tn + 64];
#pragma unroll
            for (int i = 0; i < 8; ++i)
#pragma unroll
                for (int j = 0; j < 8; ++j)
                    acc[i][j] = fmaf(a[i], b[j], acc[i][j]);
        }

#pragma unroll
        for (int j = 0; j < 8; ++j) { ra[j] = ra2[j]; rw[j] = rw2[j]; }
    }

    // epilogue
    float bv[8];
#pragma unroll
    for (int j = 0; j < 8; ++j) {
        int n = bn + ((j < 4) ? (tn + j) : (64 + tn + j - 4));
        bv[j] = bias[n];
    }

#pragma unroll
    for (int i = 0; i < 8; ++i) {
        int m = bm + ((i < 4) ? (tm + i) : (64 + tm + i - 4));
        float v[8];
#pragma unroll
        for (int j = 0; j < 8; ++j) v[j] = acc[i][j] + bv[j];

        if (MODE == 0) {
#pragma unroll
            for (int j = 0; j < 8; ++j) v[j] = fmaxf(v[j], 0.0f);
            float* Crow = C + (size_t)m * ldc;
            *(float4*)(Crow + bn + tn)      = *(float4*)&v[0];
            *(float4*)(Crow + bn + 64 + tn) = *(float4*)&v[4];
        } else if (MODE == 3) {
#pragma unroll
            for (int j = 0; j < 8; ++j) v[j] = tanhf(v[j]);
            float* Crow = C + (size_t)m * ldc;
            *(float4*)(Crow + bn + tn)      = *(float4*)&v[0];
            *(float4*)(Crow + bn + 64 + tn) = *(float4*)&v[4];
        } else { // MODE 1
            if (bn < 256) {
                float* Crow = C + (size_t)m * ldc;   // mu, ldc = 256
                *(float4*)(Crow + bn + tn)      = *(float4*)&v[0];
                *(float4*)(Crow + bn + 64 + tn) = *(float4*)&v[4];
            } else {
                float rs = 0.0f;
#pragma unroll
                for (int j = 0; j < 8; ++j) {
                    float lv = fminf(fmaxf(v[j], LOG_MIN_F), -LOG_MIN_F);
                    rs += 0.5f * __expf(lv) - 0.5f * lv - 0.5f;
                }
                atomicAdd(&S[m], rs * (1.0f / (float)LATENT));
            }
        }
    }
}

// ---------------------------------------------------------------------------
// per-row prototype math: one wave per row
// out[b] = sum_p sim * W_last[idx];  klrow[b] = sum klw / sum sim*mask
// (NO same-address atomics here — that serialized at 14 ns/atomic x 16384)
// ---------------------------------------------------------------------------
__global__ __launch_bounds__(256)
void proto_kernel(const float* __restrict__ mu, const float* __restrict__ S,
                  const int* __restrict__ tcls, const float* __restrict__ protos,
                  const float* __restrict__ Wlast, float* __restrict__ out,
                  float* __restrict__ klrow)
{
    int wave = (blockIdx.x * blockDim.x + threadIdx.x) >> 6;
    int lane = threadIdx.x & 63;
    if (wave >= B_ROWS) return;
    int b = wave;

    const float* murow = mu + (size_t)b * LATENT;
    float m0 = murow[lane];
    float m1 = murow[lane + 64];
    float m2 = murow[lane + 128];
    float m3 = murow[lane + 192];

    int cls = tcls[b];
    const float* pbase = protos + (size_t)cls * PC * LATENT;
    float Sb = S[b];

    float outv = 0.0f, num = 0.0f, den = 0.0f;
#pragma unroll
    for (int p = 0; p < PC; ++p) {
        const float* pr = pbase + p * LATENT;
        float d0 = m0 - pr[lane];
        float d1 = m1 - pr[lane + 64];
        float d2 = m2 - pr[lane + 128];
        float d3 = m3 - pr[lane + 192];
        float dd = d0 * d0 + d1 * d1 + d2 * d2 + d3 * d3;
#pragma unroll
        for (int off = 32; off; off >>= 1) dd += __shfl_xor(dd, off, 64);
        float d   = sqrtf(dd);
        float sim = logf((d + 1.0f) / (d + EPS_SIM));
        float kl  = Sb + dd * (0.5f / (float)LATENT);
        float klw = kl * sim;
        num += klw;
        den += (klw > 0.0f) ? sim : 0.0f;
        outv += sim * Wlast[cls * PC + p];
    }
    if (lane == 0) {
        out[b] = outv;
        klrow[b] = num / den;
    }
}

// ---------------------------------------------------------------------------
// kl reduction: 64 blocks x 256 threads covers 16384 rows exactly;
// wave shfl-reduce -> LDS -> ONE atomic per block (64 total)
// ---------------------------------------------------------------------------
__global__ __launch_bounds__(256)
void reduce_kl(const float* __restrict__ klrow, float* __restrict__ kl_out)
{
    int i = blockIdx.x * 256 + threadIdx.x;
    float v = klrow[i];
#pragma unroll
    for (int off = 32; off; off >>= 1) v += __shfl_xor(v, off, 64);

    __shared__ float red[4];
    int lane = threadIdx.x & 63, w = threadIdx.x >> 6;
    if (lane == 0) red[w] = v;
    __syncthreads();
    if (threadIdx.x == 0)
        atomicAdd(kl_out, (red[0] + red[1] + red[2] + red[3]) * (1.0f / (float)B_ROWS));
}

// ---------------------------------------------------------------------------
// ortho loss: one block per class
// ---------------------------------------------------------------------------
__global__ __launch_bounds__(256)
void ortho_kernel(const float* __restrict__ protos, float* __restrict__ ortho_out)
{
    int c = blockIdx.x;
    __shared__ float pk[PC][LATENT + 1];
    __shared__ float red[256];
    int t = threadIdx.x;

    for (int i = t; i < PC * LATENT; i += 256)
        pk[i >> 8][i & 255] = protos[c * PC * LATENT + i];
    __syncthreads();

    // center column t across the 16 prototypes (t in [0,256))
    float mean = 0.0f;
    for (int i = 0; i < PC; ++i) mean += pk[i][t];
    mean *= (1.0f / (float)PC);
    for (int i = 0; i < PC; ++i) pk[i][t] -= mean;
    __syncthreads();

    int i = t >> 4, j = t & 15;
    float g = 0.0f;
    for (int l = 0; l < LATENT; ++l) g += pk[i][l] * pk[j][l];
    g -= (i == j) ? 1.0f : 0.0f;

    red[t] = g * g;
    __syncthreads();
    for (int s = 128; s; s >>= 1) {
        if (t < s) red[t] += red[t + s];
        __syncthreads();
    }
    if (t == 0) atomicAdd(ortho_out, sqrtf(red[0]) * (1.0f / 8.0f));
}

// ---------------------------------------------------------------------------
extern "C" void kernel_launch(void* const* d_in, const int* in_sizes, int n_in,
                              void* d_out, int out_size, void* d_ws, size_t ws_size,
                              hipStream_t stream)
{
    const float* x      = (const float*)d_in[0];
    const int*   tcls   = (const int*)  d_in[1];
    const float* protos = (const float*)d_in[2];
    const float* W1     = (const float*)d_in[3];
    const float* b1     = (const float*)d_in[4];
    const float* W2     = (const float*)d_in[5];
    const float* b2     = (const float*)d_in[6];
    const float* Wd1    = (const float*)d_in[7];
    const float* bd1    = (const float*)d_in[8];
    const float* Wd2    = (const float*)d_in[9];
    const float* bd2    = (const float*)d_in[10];
    const float* Wlast  = (const float*)d_in[11];

    float* out     = (float*)d_out;
    float* decoded = out + B_ROWS;

    float* ws    = (float*)d_ws;
    float* h     = ws;                                    // B x 512 (reused as dh later)
    float* mu    = ws + (size_t)B_ROWS * IN_SIZE;         // B x 256
    float* S     = mu + (size_t)B_ROWS * LATENT;          // B
    float* klrow = S + B_ROWS;                            // B
    float* dh    = ws;                                    // B x 256 (overwrites h)

    hipLaunchKernelGGL(init_kernel, dim3(64), dim3(256), 0, stream, S, out);

    // h = relu(x @ W1^T + b1)
    hipLaunchKernelGGL((gemm_nt<0>), dim3(B_ROWS / BM, IN_SIZE / BN), dim3(256), 0, stream,
                       x, W1, b1, h, (float*)nullptr, IN_SIZE, IN_SIZE);
    // conv = h @ W2^T + b2 -> mu (cols<256), S (cols>=256)
    hipLaunchKernelGGL((gemm_nt<1>), dim3(B_ROWS / BM, IN_SIZE / BN), dim3(256), 0, stream,
                       h, W2, b2, mu, S, IN_SIZE, LATENT);
    // prototype distances, sim, out, per-row kl
    hipLaunchKernelGGL(proto_kernel, dim3(B_ROWS / 4), dim3(256), 0, stream,
                       mu, S, tcls, protos, Wlast, out, klrow);
    // kl_loss = mean(klrow)
    hipLaunchKernelGGL(reduce_kl, dim3(64), dim3(256), 0, stream, klrow, out + KL_IDX);
    // dh = relu(mu @ Wd1^T + bd1)
    hipLaunchKernelGGL((gemm_nt<0>), dim3(B_ROWS / BM, LATENT / BN), dim3(256), 0, stream,
                       mu, Wd1, bd1, dh, (float*)nullptr, LATENT, LATENT);
    // decoded = tanh(dh @ Wd2^T + bd2)
    hipLaunchKernelGGL((gemm_nt<3>), dim3(B_ROWS / BM, IN_SIZE / BN), dim3(256), 0, stream,
                       dh, Wd2, bd2, decoded, (float*)nullptr, LATENT, IN_SIZE);
    // ortho loss
    hipLaunchKernelGGL(ortho_kernel, dim3(8), dim3(256), 0, stream, protos, out + OR_IDX);
}

// Round 3
// 165.903 us; speedup vs baseline: 3.2012x; 2.1161x over previous
//
#include <hip/hip_runtime.h>
#include <math.h>

typedef unsigned short u16;
typedef unsigned int   u32;
typedef __bf16 bf16x8 __attribute__((ext_vector_type(8)));
typedef float  f32x4  __attribute__((ext_vector_type(4)));

#define B_ROWS 16384
#define PC 16
#define EPS_SIM 1e-4f
#define LOG_MIN_F (-18.420680743952367f)
#define KL_IDX  (B_ROWS + B_ROWS * 512)   // 8404992
#define OR_IDX  (KL_IDX + 1)

// direct global->LDS async copy, 16B per lane (lds dest = uniform base + lane*16)
#define GLD16(gp, lp) __builtin_amdgcn_global_load_lds( \
    (const __attribute__((address_space(1))) void*)(gp), \
    (__attribute__((address_space(3))) void*)(lp), 16, 0, 0)

__device__ inline u16 f2bf(float f) {
    u32 u = __float_as_uint(f);
    return (u16)((u + 0x7FFFu + ((u >> 16) & 1u)) >> 16);
}
__device__ inline float bf2f(u16 h) { return __uint_as_float(((u32)h) << 16); }

// ---------------------------------------------------------------------------
__global__ void init_kernel(float* __restrict__ S, float* __restrict__ out)
{
    int i = blockIdx.x * 256 + threadIdx.x;
    if (i < B_ROWS) S[i] = 0.0f;
    if (i == 0) { out[KL_IDX] = 0.0f; out[OR_IDX] = 0.0f; }
}

// fp32 -> (bf16 hi, bf16 lo) arrays, 4 elems/thread
__global__ __launch_bounds__(256)
void split_kernel(const float* __restrict__ src, u16* __restrict__ hi,
                  u16* __restrict__ lo, int n4)
{
    int i = blockIdx.x * 256 + threadIdx.x;
    if (i >= n4) return;
    float4 v = ((const float4*)src)[i];
    float f[4] = {v.x, v.y, v.z, v.w};
    u16 h[4], l[4];
#pragma unroll
    for (int k = 0; k < 4; ++k) {
        h[k] = f2bf(f[k]);
        l[k] = f2bf(f[k] - bf2f(h[k]));
    }
    ((ushort4*)hi)[i] = make_ushort4(h[0], h[1], h[2], h[3]);
    ((ushort4*)lo)[i] = make_ushort4(l[0], l[1], l[2], l[3]);
}

// ---------------------------------------------------------------------------
// Split-bf16 MFMA GEMM: C[M x ldc] = epi(A @ B^T + bias)
// A: hi/lo bf16 [M][K], B: hi/lo bf16 [N][K].  128x128 tile, BK=32, 4 waves.
// MODE 0: relu -> split store    MODE 3: tanh -> f32 store
// MODE 4: blockIdx.y<2 -> split store (mu); y>=2 -> logVar S row-reduction
// ---------------------------------------------------------------------------
template<int MODE>
__global__ __launch_bounds__(256, 2)
void gemm_mfma(const u16* __restrict__ Ah_g, const u16* __restrict__ Al_g,
               const u16* __restrict__ Bh_g, const u16* __restrict__ Bl_g,
               const float* __restrict__ bias,
               u16* __restrict__ Ch, u16* __restrict__ Cl,
               float* __restrict__ Cf, float* __restrict__ Srow,
               int K, int ldc)
{
    __shared__ __align__(16) u16 LAh[2][128][32];
    __shared__ __align__(16) u16 LAl[2][128][32];
    __shared__ __align__(16) u16 LBh[2][128][32];
    __shared__ __align__(16) u16 LBl[2][128][32];

    const int t = threadIdx.x, lane = t & 63, wave = t >> 6;
    const int wm = wave >> 1, wn = wave & 1;
    const int bm = blockIdx.x * 128, bn = blockIdx.y * 128;
    const int rA = lane & 15, g = lane >> 4;

    // staging: lane -> (row-in-16-slab, physical 16B chunk)
    const int srow = lane >> 2, cp = lane & 3;

    f32x4 acc[4][4];
    const f32x4 z4 = {0.f, 0.f, 0.f, 0.f};
#pragma unroll
    for (int i = 0; i < 4; ++i)
#pragma unroll
        for (int j = 0; j < 4; ++j) acc[i][j] = z4;

    auto stage = [&](int buf, int kt) {
#pragma unroll
        for (int j = 0; j < 2; ++j) {
            int row = wave * 32 + j * 16 + srow;
            int lc  = (cp - (row >> 1)) & 3;              // inverse swizzle on SOURCE
            size_t goffA = (size_t)(bm + row) * K + kt * 32 + lc * 8;
            size_t goffB = (size_t)(bn + row) * K + kt * 32 + lc * 8;
            u16* dA = &LAh[buf][wave * 32 + j * 16][0];
            u16* dAl= &LAl[buf][wave * 32 + j * 16][0];
            u16* dB = &LBh[buf][wave * 32 + j * 16][0];
            u16* dBl= &LBl[buf][wave * 32 + j * 16][0];
            GLD16(Ah_g + goffA, dA);
            GLD16(Al_g + goffA, dAl);
            GLD16(Bh_g + goffB, dB);
            GLD16(Bl_g + goffB, dBl);
        }
    };

    const int T = K / 32;
    stage(0, 0);
    for (int tk = 0; tk < T; ++tk) {
        __syncthreads();                       // drains vmcnt: buf[tk&1] ready
        if (tk + 1 < T) stage((tk + 1) & 1, tk + 1);
        const int buf = tk & 1;

        bf16x8 aH[4], aL[4], bH[4], bL[4];
#pragma unroll
        for (int f = 0; f < 4; ++f) {
            int m  = wm * 64 + f * 16 + rA;
            int cm = ((g + (m >> 1)) & 3) * 8;            // swizzled READ
            aH[f] = *(const bf16x8*)&LAh[buf][m][cm];
            aL[f] = *(const bf16x8*)&LAl[buf][m][cm];
            int n  = wn * 64 + f * 16 + rA;
            int cn = ((g + (n >> 1)) & 3) * 8;
            bH[f] = *(const bf16x8*)&LBh[buf][n][cn];
            bL[f] = *(const bf16x8*)&LBl[buf][n][cn];
        }
#pragma unroll
        for (int i = 0; i < 4; ++i)
#pragma unroll
            for (int j = 0; j < 4; ++j) {
                acc[i][j] = __builtin_amdgcn_mfma_f32_16x16x32_bf16(aH[i], bH[j], acc[i][j], 0, 0, 0);
                acc[i][j] = __builtin_amdgcn_mfma_f32_16x16x32_bf16(aL[i], bH[j], acc[i][j], 0, 0, 0);
                acc[i][j] = __builtin_amdgcn_mfma_f32_16x16x32_bf16(aH[i], bL[j], acc[i][j], 0, 0, 0);
            }
    }

    float bv[4];
#pragma unroll
    for (int j = 0; j < 4; ++j) bv[j] = bias[bn + wn * 64 + j * 16 + rA];

    if (MODE == 4 && blockIdx.y >= 2) {
        // logVar columns: S[row] += mean_l(0.5 e^lv - 0.5 lv - 0.5)
#pragma unroll
        for (int i = 0; i < 4; ++i)
#pragma unroll
            for (int r = 0; r < 4; ++r) {
                int row = bm + wm * 64 + i * 16 + g * 4 + r;
                float s = 0.f;
#pragma unroll
                for (int j = 0; j < 4; ++j) {
                    float lv = acc[i][j][r] + bv[j];
                    lv = fminf(fmaxf(lv, LOG_MIN_F), -LOG_MIN_F);
                    s += 0.5f * __expf(lv) - 0.5f * lv - 0.5f;
                }
                s += __shfl_xor(s, 1, 64); s += __shfl_xor(s, 2, 64);
                s += __shfl_xor(s, 4, 64); s += __shfl_xor(s, 8, 64);
                if (rA == 0) atomicAdd(&Srow[row], s * (1.f / 256.f));
            }
        return;
    }

#pragma unroll
    for (int i = 0; i < 4; ++i)
#pragma unroll
        for (int r = 0; r < 4; ++r) {
            size_t row = bm + wm * 64 + i * 16 + g * 4 + r;
#pragma unroll
            for (int j = 0; j < 4; ++j) {
                int col = bn + wn * 64 + j * 16 + rA;
                float v = acc[i][j][r] + bv[j];
                if (MODE == 0) v = fmaxf(v, 0.f);
                if (MODE == 3) {
                    float e = __expf(2.f * v);
                    Cf[row * ldc + col] = 1.f - 2.f / (e + 1.f);
                } else {
                    u16 hh = f2bf(v);
                    u16 ll = f2bf(v - bf2f(hh));
                    Ch[row * ldc + col] = hh;
                    Cl[row * ldc + col] = ll;
                }
            }
        }
}

// ---------------------------------------------------------------------------
// per-row prototype math: one wave per row (mu read as hi+lo bf16 pair)
// ---------------------------------------------------------------------------
__global__ __launch_bounds__(256)
void proto_kernel(const u16* __restrict__ mu_h, const u16* __restrict__ mu_l,
                  const float* __restrict__ S, const int* __restrict__ tcls,
                  const float* __restrict__ protos, const float* __restrict__ Wlast,
                  float* __restrict__ out, float* __restrict__ klrow)
{
    int wv = (blockIdx.x * 256 + threadIdx.x) >> 6;
    int lane = threadIdx.x & 63;
    if (wv >= B_ROWS) return;
    int b = wv;
    size_t base = (size_t)b * 256;

    float m0 = bf2f(mu_h[base + lane])       + bf2f(mu_l[base + lane]);
    float m1 = bf2f(mu_h[base + lane + 64])  + bf2f(mu_l[base + lane + 64]);
    float m2 = bf2f(mu_h[base + lane + 128]) + bf2f(mu_l[base + lane + 128]);
    float m3 = bf2f(mu_h[base + lane + 192]) + bf2f(mu_l[base + lane + 192]);

    int cls = tcls[b];
    const float* pbase = protos + (size_t)cls * PC * 256;
    float Sb = S[b];

    float outv = 0.f, num = 0.f, den = 0.f;
#pragma unroll
    for (int p = 0; p < PC; ++p) {
        const float* pr = pbase + p * 256;
        float d0 = m0 - pr[lane];
        float d1 = m1 - pr[lane + 64];
        float d2 = m2 - pr[lane + 128];
        float d3 = m3 - pr[lane + 192];
        float dd = d0 * d0 + d1 * d1 + d2 * d2 + d3 * d3;
#pragma unroll
        for (int off = 32; off; off >>= 1) dd += __shfl_xor(dd, off, 64);
        float d   = sqrtf(dd);
        float sim = logf((d + 1.0f) / (d + EPS_SIM));
        float kl  = Sb + dd * (0.5f / 256.f);
        float klw = kl * sim;
        num += klw;
        den += (klw > 0.0f) ? sim : 0.0f;
        outv += sim * Wlast[cls * PC + p];
    }
    if (lane == 0) {
        out[b] = outv;
        klrow[b] = num / den;
    }
}

__global__ __launch_bounds__(256)
void reduce_kl(const float* __restrict__ klrow, float* __restrict__ kl_out)
{
    int i = blockIdx.x * 256 + threadIdx.x;
    float v = klrow[i];
#pragma unroll
    for (int off = 32; off; off >>= 1) v += __shfl_xor(v, off, 64);
    __shared__ float red[4];
    int lane = threadIdx.x & 63, w = threadIdx.x >> 6;
    if (lane == 0) red[w] = v;
    __syncthreads();
    if (threadIdx.x == 0)
        atomicAdd(kl_out, (red[0] + red[1] + red[2] + red[3]) * (1.0f / (float)B_ROWS));
}

__global__ __launch_bounds__(256)
void ortho_kernel(const float* __restrict__ protos, float* __restrict__ ortho_out)
{
    int c = blockIdx.x;
    __shared__ float pk[PC][257];
    __shared__ float red[256];
    int t = threadIdx.x;
    for (int i = t; i < PC * 256; i += 256)
        pk[i >> 8][i & 255] = protos[c * PC * 256 + i];
    __syncthreads();
    float mean = 0.0f;
    for (int i = 0; i < PC; ++i) mean += pk[i][t];
    mean *= (1.0f / (float)PC);
    for (int i = 0; i < PC; ++i) pk[i][t] -= mean;
    __syncthreads();
    int i = t >> 4, j = t & 15;
    float gg = 0.0f;
    for (int l = 0; l < 256; ++l) gg += pk[i][l] * pk[j][l];
    gg -= (i == j) ? 1.0f : 0.0f;
    red[t] = gg * gg;
    __syncthreads();
    for (int s = 128; s; s >>= 1) { if (t < s) red[t] += red[t + s]; __syncthreads(); }
    if (t == 0) atomicAdd(ortho_out, sqrtf(red[0]) * (1.0f / 8.0f));
}

// ---------------------------------------------------------------------------
extern "C" void kernel_launch(void* const* d_in, const int* in_sizes, int n_in,
                              void* d_out, int out_size, void* d_ws, size_t ws_size,
                              hipStream_t stream)
{
    const float* x      = (const float*)d_in[0];
    const int*   tcls   = (const int*)  d_in[1];
    const float* protos = (const float*)d_in[2];
    const float* W1     = (const float*)d_in[3];
    const float* b1     = (const float*)d_in[4];
    const float* W2     = (const float*)d_in[5];
    const float* b2     = (const float*)d_in[6];
    const float* Wd1    = (const float*)d_in[7];
    const float* bd1    = (const float*)d_in[8];
    const float* Wd2    = (const float*)d_in[9];
    const float* bd2    = (const float*)d_in[10];
    const float* Wlast  = (const float*)d_in[11];

    float* out     = (float*)d_out;
    float* decoded = out + B_ROWS;

    // h (split bf16) lives in d_out's decoded region (33.55MB), overwritten by G4
    u16* h_h = (u16*)decoded;
    u16* h_l = h_h + 8388608;

    // workspace overlays: x2 region (33.55MB) reused for mu2 + dh2 after G1
    u16* wsu  = (u16*)d_ws;
    u16* x_h  = wsu;
    u16* x_l  = wsu + 8388608;
    u16* mu_h = wsu;
    u16* mu_l = wsu + 4194304;
    u16* dh_h = wsu + 8388608;
    u16* dh_l = wsu + 12582912;

    float* S     = (float*)((char*)d_ws + 33554432);
    float* klrow = S + 16384;
    u16* w = (u16*)(klrow + 16384);
    u16 *W1h = w, *W1l = w + 262144, *W2h = w + 524288, *W2l = w + 786432;
    u16 *Wd1h = w + 1048576, *Wd1l = w + 1114112, *Wd2h = w + 1179648, *Wd2l = w + 1310720;

    hipLaunchKernelGGL(init_kernel, dim3(64), dim3(256), 0, stream, S, out);

    hipLaunchKernelGGL(split_kernel, dim3(8192), dim3(256), 0, stream, x,   x_h,  x_l,  2097152);
    hipLaunchKernelGGL(split_kernel, dim3(256),  dim3(256), 0, stream, W1,  W1h,  W1l,  65536);
    hipLaunchKernelGGL(split_kernel, dim3(256),  dim3(256), 0, stream, W2,  W2h,  W2l,  65536);
    hipLaunchKernelGGL(split_kernel, dim3(64),   dim3(256), 0, stream, Wd1, Wd1h, Wd1l, 16384);
    hipLaunchKernelGGL(split_kernel, dim3(128),  dim3(256), 0, stream, Wd2, Wd2h, Wd2l, 32768);

    // G1: h = relu(x @ W1^T + b1) -> split bf16
    hipLaunchKernelGGL((gemm_mfma<0>), dim3(128, 4), dim3(256), 0, stream,
                       x_h, x_l, W1h, W1l, b1, h_h, h_l, (float*)nullptr, (float*)nullptr, 512, 512);
    // G2: conv = h @ W2^T + b2 -> mu split (y<2) + S row-sums (y>=2)
    hipLaunchKernelGGL((gemm_mfma<4>), dim3(128, 4), dim3(256), 0, stream,
                       h_h, h_l, W2h, W2l, b2, mu_h, mu_l, (float*)nullptr, S, 512, 256);
    // prototype distances, sim, out, per-row kl
    hipLaunchKernelGGL(proto_kernel, dim3(B_ROWS / 4), dim3(256), 0, stream,
                       mu_h, mu_l, S, tcls, protos, Wlast, out, klrow);
    hipLaunchKernelGGL(reduce_kl, dim3(64), dim3(256), 0, stream, klrow, out + KL_IDX);
    // G3: dh = relu(mu @ Wd1^T + bd1) -> split bf16
    hipLaunchKernelGGL((gemm_mfma<0>), dim3(128, 2), dim3(256), 0, stream,
                       mu_h, mu_l, Wd1h, Wd1l, bd1, dh_h, dh_l, (float*)nullptr, (float*)nullptr, 256, 256);
    // G4: decoded = tanh(dh @ Wd2^T + bd2) -> f32 (overwrites h region)
    hipLaunchKernelGGL((gemm_mfma<3>), dim3(128, 4), dim3(256), 0, stream,
                       dh_h, dh_l, Wd2h, Wd2l, bd2, (u16*)nullptr, (u16*)nullptr, decoded, (float*)nullptr, 256, 512);
    hipLaunchKernelGGL(ortho_kernel, dim3(8), dim3(256), 0, stream, protos, out + OR_IDX);
}